// Round 5
// baseline (3017.366 us; speedup 1.0000x reference)
//
#include <hip/hip_runtime.h>
#include <hip/hip_bf16.h>

// SPRGNN: 2-layer GraphConv GNN forward. CSR-gather, bf16 activation storage,
// f32 accumulate. N=100000, E=1200000, G=1000.
//
// R5: (a) conv restructured: 4 nodes/thread so one LDS b128 weight read feeds
// 16 FMAs (R4 was 1:4 -> LDS-pipe bound, 126us @ 29% VALU). (b) h1/h2/h3/agg
// stored bf16 -> gather bytes halved. All accumulation f32.

#define NGRAPHS 1000
#define SCAN_CHUNK 4096

// ---------------------------------------------------------------- bf16 helpers
__device__ __forceinline__ float bflo(unsigned u) {
    union { unsigned i; float f; } c; c.i = u << 16; return c.f;
}
__device__ __forceinline__ float bfhi(unsigned u) {
    union { unsigned i; float f; } c; c.i = u & 0xffff0000u; return c.f;
}
__device__ __forceinline__ unsigned short f2bf(float f) {
    union { unsigned i; float f; } c; c.f = f;
    unsigned i = c.i;
    unsigned r = (i + 0x7fffu + ((i >> 16) & 1u)) >> 16;  // RNE (no NaN inputs)
    return (unsigned short)r;
}
__device__ __forceinline__ unsigned pk2(float lo, float hi) {
    return (unsigned)f2bf(lo) | ((unsigned)f2bf(hi) << 16);
}

// ---------------------------------------------------------------- CSR build
__global__ __launch_bounds__(256) void k_hist(const int* __restrict__ dst,
                                              int* __restrict__ hist, int nE)
{
    int e = blockIdx.x * 256 + threadIdx.x;
    if (e < nE) atomicAdd(&hist[dst[e]], 1);
}

__global__ __launch_bounds__(256) void k_scan_part(const int* __restrict__ hist,
                                                   int* __restrict__ bsum, int n)
{
    __shared__ int s[256];
    int t = threadIdx.x;
    int beg = blockIdx.x * SCAN_CHUNK + t * 16;
    int sum = 0;
#pragma unroll
    for (int q = 0; q < 16; ++q) {
        int i = beg + q;
        if (i < n) sum += hist[i];
    }
    s[t] = sum;
    __syncthreads();
    for (int off = 128; off > 0; off >>= 1) {
        if (t < off) s[t] += s[t + off];
        __syncthreads();
    }
    if (t == 0) bsum[blockIdx.x] = s[0];
}

__global__ __launch_bounds__(64) void k_scan_mid(const int* __restrict__ bsum,
                                                 int* __restrict__ boffs,
                                                 int* __restrict__ row_ptr,
                                                 int B, int n)
{
    if (threadIdx.x == 0) {
        int run = 0;
        for (int b = 0; b < B; ++b) {
            boffs[b] = run;
            run += bsum[b];
        }
        row_ptr[n] = run;
    }
}

__global__ __launch_bounds__(256) void k_scan_apply(const int* __restrict__ hist,
                                                    const int* __restrict__ boffs,
                                                    int* __restrict__ row_ptr,
                                                    int* __restrict__ cursor, int n)
{
    __shared__ int s[256];
    int t = threadIdx.x;
    int beg = blockIdx.x * SCAN_CHUNK + t * 16;
    int v[16];
    int sum = 0;
#pragma unroll
    for (int q = 0; q < 16; ++q) {
        int i = beg + q;
        v[q] = (i < n) ? hist[i] : 0;
        sum += v[q];
    }
    s[t] = sum;
    __syncthreads();
    for (int off = 1; off < 256; off <<= 1) {
        int x = (t >= off) ? s[t - off] : 0;
        __syncthreads();
        s[t] += x;
        __syncthreads();
    }
    int base = boffs[blockIdx.x] + ((t == 0) ? 0 : s[t - 1]);
#pragma unroll
    for (int q = 0; q < 16; ++q) {
        int i = beg + q;
        if (i < n) {
            row_ptr[i] = base;
            cursor[i] = base;
            base += v[q];
        }
    }
}

__global__ __launch_bounds__(256) void k_scatteridx(
    const int* __restrict__ src, const int* __restrict__ dst,
    int* __restrict__ cursor, int* __restrict__ sorted_src, int nE)
{
    int e = blockIdx.x * 256 + threadIdx.x;
    if (e >= nE) return;
    int pos = atomicAdd(&cursor[dst[e]], 1);
    sorted_src[pos] = src[e];
}

// ---------------------------------------------------------------- K1: pre-MLP
__global__ __launch_bounds__(256) void k_pre(
    const int* __restrict__ x,
    const float* __restrict__ shape_emb, const float* __restrict__ color_emb,
    const float* __restrict__ W_pre, const float* __restrict__ b_pre,
    unsigned short* __restrict__ h1, int n)
{
    __shared__ float sW[32 * 16];
    __shared__ float sB[32];
    __shared__ float sSE[16 * 8];
    __shared__ float sCE[8 * 8];
    int t = threadIdx.x;
    for (int i = t; i < 32 * 16; i += 256) sW[i] = W_pre[i];
    if (t < 32) sB[t] = b_pre[t];
    for (int i = t; i < 16 * 8; i += 256) sSE[i] = shape_emb[i];
    if (t < 64) sCE[t] = color_emb[t];
    __syncthreads();

    int i = blockIdx.x * 256 + t;
    if (i >= n) return;
    int s = x[2 * i];
    int c = x[2 * i + 1];
    float in[16];
#pragma unroll
    for (int k = 0; k < 8; ++k) in[k] = sSE[s * 8 + k];
#pragma unroll
    for (int k = 0; k < 8; ++k) in[8 + k] = sCE[c * 8 + k];

    float acc[32];
#pragma unroll
    for (int j = 0; j < 32; ++j) acc[j] = sB[j];
#pragma unroll
    for (int k = 0; k < 16; ++k) {
        float v = in[k];
#pragma unroll
        for (int j = 0; j < 32; ++j) acc[j] += sW[j * 16 + k] * v;
    }
    unsigned w[16];
#pragma unroll
    for (int jp = 0; jp < 16; ++jp)
        w[jp] = pk2(fmaxf(acc[2 * jp], 0.f), fmaxf(acc[2 * jp + 1], 0.f));
    uint4* op = (uint4*)(h1 + (size_t)i * 32);
    op[0] = make_uint4(w[0], w[1], w[2], w[3]);
    op[1] = make_uint4(w[4], w[5], w[6], w[7]);
    op[2] = make_uint4(w[8], w[9], w[10], w[11]);
    op[3] = make_uint4(w[12], w[13], w[14], w[15]);
}

// ------------------------------------------------- gather aggregation via CSR
// PARTS threads/node; each owns 8 bf16 channels (16B). f32 accumulate,
// bf16 write. Edge loop unrolled x2 for two gathers in flight.
template <int WIDTH, int PARTS>
__global__ __launch_bounds__(256) void k_agg(
    const int* __restrict__ row_ptr, const int* __restrict__ sorted_src,
    const unsigned short* __restrict__ h, unsigned short* __restrict__ agg, int n)
{
    int tid = blockIdx.x * 256 + threadIdx.x;
    int i = tid / PARTS;
    int p = tid % PARTS;
    if (i >= n) return;
    float a[8] = {0, 0, 0, 0, 0, 0, 0, 0};
    float b[8] = {0, 0, 0, 0, 0, 0, 0, 0};
    int e0 = row_ptr[i], e1 = row_ptr[i + 1];
    const unsigned short* hp = h + p * 8;
    int e = e0;
    for (; e + 2 <= e1; e += 2) {
        int s0 = sorted_src[e];
        int s1 = sorted_src[e + 1];
        uint4 r0 = *(const uint4*)(hp + (size_t)s0 * WIDTH);
        uint4 r1 = *(const uint4*)(hp + (size_t)s1 * WIDTH);
        a[0] += bflo(r0.x); a[1] += bfhi(r0.x); a[2] += bflo(r0.y); a[3] += bfhi(r0.y);
        a[4] += bflo(r0.z); a[5] += bfhi(r0.z); a[6] += bflo(r0.w); a[7] += bfhi(r0.w);
        b[0] += bflo(r1.x); b[1] += bfhi(r1.x); b[2] += bflo(r1.y); b[3] += bfhi(r1.y);
        b[4] += bflo(r1.z); b[5] += bfhi(r1.z); b[6] += bflo(r1.w); b[7] += bfhi(r1.w);
    }
    if (e < e1) {
        int s0 = sorted_src[e];
        uint4 r0 = *(const uint4*)(hp + (size_t)s0 * WIDTH);
        a[0] += bflo(r0.x); a[1] += bfhi(r0.x); a[2] += bflo(r0.y); a[3] += bfhi(r0.y);
        a[4] += bflo(r0.z); a[5] += bfhi(r0.z); a[6] += bflo(r0.w); a[7] += bfhi(r0.w);
    }
#pragma unroll
    for (int q = 0; q < 8; ++q) a[q] += b[q];
    uint4* ap = (uint4*)(agg + (size_t)i * WIDTH + p * 8);
    *ap = make_uint4(pk2(a[0], a[1]), pk2(a[2], a[3]), pk2(a[4], a[5]), pk2(a[6], a[7]));
}

// ---------------------------------------------------- conv (weight-amortized)
// Block = 256 thr = 4 waves; wave wq owns output channels [wq*16, wq*16+16).
// Each thread processes 4 nodes (i = base + nn*64 + lane) -> one LDS b128
// weight read feeds 16 FMAs. acc[4][16] f32; bf16 in/out.
template <int WIN>
__global__ __launch_bounds__(256) void k_conv(
    const unsigned short* __restrict__ agg, const unsigned short* __restrict__ h,
    const float* __restrict__ W_rel, const float* __restrict__ b_rel,
    const float* __restrict__ W_root, unsigned short* __restrict__ out, int n)
{
    __shared__ float sWrel[64 * WIN];
    __shared__ float sWroot[64 * WIN];
    __shared__ float sB[64];
    int t = threadIdx.x;
    for (int i = t; i < 64 * WIN; i += 256) {
        sWrel[i] = W_rel[i];
        sWroot[i] = W_root[i];
    }
    if (t < 64) sB[t] = b_rel[t];
    __syncthreads();

    int lane = t & 63;
    int wq = t >> 6;
    int base = blockIdx.x * 256;

    float acc[4][16];
#pragma unroll
    for (int nn = 0; nn < 4; ++nn)
#pragma unroll
        for (int j = 0; j < 16; ++j) acc[nn][j] = sB[wq * 16 + j];

    const float* wr = sWrel + (size_t)(wq * 16) * WIN;
    const float* wo = sWroot + (size_t)(wq * 16) * WIN;

#pragma unroll
    for (int kc = 0; kc < WIN / 4; ++kc) {
        float av[4][4], hv[4][4];
#pragma unroll
        for (int nn = 0; nn < 4; ++nn) {
            int i = base + nn * 64 + lane;
            if (i < n) {
                uint2 ua = *(const uint2*)(agg + (size_t)i * WIN + kc * 4);
                uint2 uh = *(const uint2*)(h + (size_t)i * WIN + kc * 4);
                av[nn][0] = bflo(ua.x); av[nn][1] = bfhi(ua.x);
                av[nn][2] = bflo(ua.y); av[nn][3] = bfhi(ua.y);
                hv[nn][0] = bflo(uh.x); hv[nn][1] = bfhi(uh.x);
                hv[nn][2] = bflo(uh.y); hv[nn][3] = bfhi(uh.y);
            } else {
#pragma unroll
                for (int q = 0; q < 4; ++q) { av[nn][q] = 0.f; hv[nn][q] = 0.f; }
            }
        }
#pragma unroll
        for (int j = 0; j < 16; ++j) {
            float4 w4 = *(const float4*)(wr + (size_t)j * WIN + kc * 4);
            float4 o4 = *(const float4*)(wo + (size_t)j * WIN + kc * 4);
#pragma unroll
            for (int nn = 0; nn < 4; ++nn) {
                acc[nn][j] += w4.x * av[nn][0] + o4.x * hv[nn][0];
                acc[nn][j] += w4.y * av[nn][1] + o4.y * hv[nn][1];
                acc[nn][j] += w4.z * av[nn][2] + o4.z * hv[nn][2];
                acc[nn][j] += w4.w * av[nn][3] + o4.w * hv[nn][3];
            }
        }
    }

#pragma unroll
    for (int nn = 0; nn < 4; ++nn) {
        int i = base + nn * 64 + lane;
        if (i >= n) continue;
        unsigned w[8];
#pragma unroll
        for (int jp = 0; jp < 8; ++jp)
            w[jp] = pk2(fmaxf(acc[nn][2 * jp], 0.f), fmaxf(acc[nn][2 * jp + 1], 0.f));
        uint4* op = (uint4*)(out + (size_t)i * 64 + wq * 16);
        op[0] = make_uint4(w[0], w[1], w[2], w[3]);
        op[1] = make_uint4(w[4], w[5], w[6], w[7]);
    }
}

// ------------------------------------------- pool (block per graph) + classifier
__global__ __launch_bounds__(256) void k_pool_cls(
    const unsigned short* __restrict__ h3, const int* __restrict__ batch,
    const float* __restrict__ W_cls, const float* __restrict__ b_cls,
    float* __restrict__ out, int n)
{
    __shared__ float part[4][64];
    __shared__ float pool[64];
    __shared__ int range[2];
    int g = blockIdx.x;
    int t = threadIdx.x;

    if (t < 2) {
        int key = g + t;
        int lo = 0, hi = n;
        while (lo < hi) {
            int mid = (lo + hi) >> 1;
            if (batch[mid] < key) lo = mid + 1; else hi = mid;
        }
        range[t] = lo;
    }
    __syncthreads();
    int start = range[0], end = range[1];

    int j = t & 63;
    int sub = t >> 6;
    float local = 0.f;
    for (int i = start + sub; i < end; i += 4) {
        unsigned short u = h3[(size_t)i * 64 + j];
        local += bflo((unsigned)u);
    }
    part[sub][j] = local;
    __syncthreads();

    if (t < 64) {
        float cnt = (float)(end - start);
        float inv = 1.0f / fmaxf(cnt, 1.0f);
        pool[t] = (part[0][t] + part[1][t] + part[2][t] + part[3][t]) * inv;
    }
    __syncthreads();

    if (t < 10) {
        float acc = b_cls[t];
#pragma unroll
        for (int k = 0; k < 64; ++k) acc += W_cls[t * 64 + k] * pool[k];
        out[(size_t)g * 10 + t] = acc;
    }
}

// ---------------------------------------------------------------- launch
extern "C" void kernel_launch(void* const* d_in, const int* in_sizes, int n_in,
                              void* d_out, int out_size, void* d_ws, size_t ws_size,
                              hipStream_t stream)
{
    const int* x        = (const int*)d_in[0];
    const int* ei       = (const int*)d_in[1];
    const int* batch    = (const int*)d_in[2];
    const float* shape_emb = (const float*)d_in[4];
    const float* color_emb = (const float*)d_in[5];
    const float* W_pre   = (const float*)d_in[6];
    const float* b_pre   = (const float*)d_in[7];
    const float* W_rel1  = (const float*)d_in[8];
    const float* b_rel1  = (const float*)d_in[9];
    const float* W_root1 = (const float*)d_in[10];
    const float* W_rel2  = (const float*)d_in[11];
    const float* b_rel2  = (const float*)d_in[12];
    const float* W_root2 = (const float*)d_in[13];
    const float* W_cls   = (const float*)d_in[14];
    const float* b_cls   = (const float*)d_in[15];

    const int n  = in_sizes[0] / 2;   // 100000
    const int nE = in_sizes[1] / 2;   // 1200000
    const int G  = NGRAPHS;
    const int* src = ei;
    const int* dst = ei + nE;

    // workspace (bytes): bf16 buffers then ints, all disjoint.
    //  h1B  [N*32 bf16]  6.4MB
    //  agg1B[N*32 bf16]  6.4MB
    //  h2B  [N*64 bf16] 12.8MB
    //  agg2B[N*64 bf16] 12.8MB
    //  h3B  [N*64 bf16] 12.8MB
    //  ints: row_ptr[n+1] | hist[n] | cursor[n] | sorted_src[E] | bsum | boffs
    unsigned short* us = (unsigned short*)d_ws;
    unsigned short* h1B   = us;
    unsigned short* agg1B = h1B + (size_t)n * 32;
    unsigned short* h2B   = agg1B + (size_t)n * 32;
    unsigned short* agg2B = h2B + (size_t)n * 64;
    unsigned short* h3B   = agg2B + (size_t)n * 64;
    int* ints       = (int*)(h3B + (size_t)n * 64);
    int* row_ptr    = ints;
    int* hist       = ints + (n + 1);
    int* cursor     = ints + (n + 1) + n;
    int* sorted_src = ints + (n + 1) + 2 * n;
    int* bsum       = sorted_src + nE;
    int* boffs      = bsum + 64;

    const int EB = (nE + 255) / 256;
    const int NB = (n + 255) / 256;
    const int CB = (n + 255) / 256;  // conv: 256 nodes/block
    const int SB = (n + SCAN_CHUNK - 1) / SCAN_CHUNK;

    // --- CSR build ---
    hipMemsetAsync(hist, 0, (size_t)n * sizeof(int), stream);
    k_hist<<<EB, 256, 0, stream>>>(dst, hist, nE);
    k_scan_part<<<SB, 256, 0, stream>>>(hist, bsum, n);
    k_scan_mid<<<1, 64, 0, stream>>>(bsum, boffs, row_ptr, SB, n);
    k_scan_apply<<<SB, 256, 0, stream>>>(hist, boffs, row_ptr, cursor, n);
    k_scatteridx<<<EB, 256, 0, stream>>>(src, dst, cursor, sorted_src, nE);

    // --- forward ---
    k_pre<<<NB, 256, 0, stream>>>(x, shape_emb, color_emb, W_pre, b_pre, h1B, n);
    k_agg<32, 4><<<((size_t)n * 4 + 255) / 256, 256, 0, stream>>>(row_ptr, sorted_src, h1B, agg1B, n);
    k_conv<32><<<CB, 256, 0, stream>>>(agg1B, h1B, W_rel1, b_rel1, W_root1, h2B, n);
    k_agg<64, 8><<<((size_t)n * 8 + 255) / 256, 256, 0, stream>>>(row_ptr, sorted_src, h2B, agg2B, n);
    k_conv<64><<<CB, 256, 0, stream>>>(agg2B, h2B, W_rel2, b_rel2, W_root2, h3B, n);
    k_pool_cls<<<G, 256, 0, stream>>>(h3B, batch, W_cls, b_cls, (float*)d_out, n);
}

// Round 6
// 2254.510 us; speedup vs baseline: 1.3384x; 1.3384x over previous
//
#include <hip/hip_runtime.h>
#include <hip/hip_bf16.h>

// SPRGNN: 2-layer GraphConv GNN forward. CSR-gather, bf16 activation storage,
// f32 accumulate. N=100000, E=1200000, G=1000.
//
// R6: conv at 2 nodes/thread (R5's 4-node version hit VGPR=256 and spilled
// 4GB scratch traffic; R4's 1-node version was LDS-pipe bound). acc[2][16]
// + small temps ~= 90 VGPR. Index-clamped loads, guarded stores (no inner
// branches). bf16 buffers + parallel scan as R5.

#define NGRAPHS 1000
#define SCAN_CHUNK 4096

// ---------------------------------------------------------------- bf16 helpers
__device__ __forceinline__ float bflo(unsigned u) {
    union { unsigned i; float f; } c; c.i = u << 16; return c.f;
}
__device__ __forceinline__ float bfhi(unsigned u) {
    union { unsigned i; float f; } c; c.i = u & 0xffff0000u; return c.f;
}
__device__ __forceinline__ unsigned short f2bf(float f) {
    union { unsigned i; float f; } c; c.f = f;
    unsigned i = c.i;
    unsigned r = (i + 0x7fffu + ((i >> 16) & 1u)) >> 16;  // RNE (no NaN inputs)
    return (unsigned short)r;
}
__device__ __forceinline__ unsigned pk2(float lo, float hi) {
    return (unsigned)f2bf(lo) | ((unsigned)f2bf(hi) << 16);
}

// ---------------------------------------------------------------- CSR build
__global__ __launch_bounds__(256) void k_hist(const int* __restrict__ dst,
                                              int* __restrict__ hist, int nE)
{
    int e = blockIdx.x * 256 + threadIdx.x;
    if (e < nE) atomicAdd(&hist[dst[e]], 1);
}

__global__ __launch_bounds__(256) void k_scan_part(const int* __restrict__ hist,
                                                   int* __restrict__ bsum, int n)
{
    __shared__ int s[256];
    int t = threadIdx.x;
    int beg = blockIdx.x * SCAN_CHUNK + t * 16;
    int sum = 0;
#pragma unroll
    for (int q = 0; q < 16; ++q) {
        int i = beg + q;
        if (i < n) sum += hist[i];
    }
    s[t] = sum;
    __syncthreads();
    for (int off = 128; off > 0; off >>= 1) {
        if (t < off) s[t] += s[t + off];
        __syncthreads();
    }
    if (t == 0) bsum[blockIdx.x] = s[0];
}

__global__ __launch_bounds__(64) void k_scan_mid(const int* __restrict__ bsum,
                                                 int* __restrict__ boffs,
                                                 int* __restrict__ row_ptr,
                                                 int B, int n)
{
    if (threadIdx.x == 0) {
        int run = 0;
        for (int b = 0; b < B; ++b) {
            boffs[b] = run;
            run += bsum[b];
        }
        row_ptr[n] = run;
    }
}

__global__ __launch_bounds__(256) void k_scan_apply(const int* __restrict__ hist,
                                                    const int* __restrict__ boffs,
                                                    int* __restrict__ row_ptr,
                                                    int* __restrict__ cursor, int n)
{
    __shared__ int s[256];
    int t = threadIdx.x;
    int beg = blockIdx.x * SCAN_CHUNK + t * 16;
    int v[16];
    int sum = 0;
#pragma unroll
    for (int q = 0; q < 16; ++q) {
        int i = beg + q;
        v[q] = (i < n) ? hist[i] : 0;
        sum += v[q];
    }
    s[t] = sum;
    __syncthreads();
    for (int off = 1; off < 256; off <<= 1) {
        int x = (t >= off) ? s[t - off] : 0;
        __syncthreads();
        s[t] += x;
        __syncthreads();
    }
    int base = boffs[blockIdx.x] + ((t == 0) ? 0 : s[t - 1]);
#pragma unroll
    for (int q = 0; q < 16; ++q) {
        int i = beg + q;
        if (i < n) {
            row_ptr[i] = base;
            cursor[i] = base;
            base += v[q];
        }
    }
}

__global__ __launch_bounds__(256) void k_scatteridx(
    const int* __restrict__ src, const int* __restrict__ dst,
    int* __restrict__ cursor, int* __restrict__ sorted_src, int nE)
{
    int e = blockIdx.x * 256 + threadIdx.x;
    if (e >= nE) return;
    int pos = atomicAdd(&cursor[dst[e]], 1);
    sorted_src[pos] = src[e];
}

// ---------------------------------------------------------------- K1: pre-MLP
__global__ __launch_bounds__(256) void k_pre(
    const int* __restrict__ x,
    const float* __restrict__ shape_emb, const float* __restrict__ color_emb,
    const float* __restrict__ W_pre, const float* __restrict__ b_pre,
    unsigned short* __restrict__ h1, int n)
{
    __shared__ float sW[32 * 16];
    __shared__ float sB[32];
    __shared__ float sSE[16 * 8];
    __shared__ float sCE[8 * 8];
    int t = threadIdx.x;
    for (int i = t; i < 32 * 16; i += 256) sW[i] = W_pre[i];
    if (t < 32) sB[t] = b_pre[t];
    for (int i = t; i < 16 * 8; i += 256) sSE[i] = shape_emb[i];
    if (t < 64) sCE[t] = color_emb[t];
    __syncthreads();

    int i = blockIdx.x * 256 + t;
    if (i >= n) return;
    int s = x[2 * i];
    int c = x[2 * i + 1];
    float in[16];
#pragma unroll
    for (int k = 0; k < 8; ++k) in[k] = sSE[s * 8 + k];
#pragma unroll
    for (int k = 0; k < 8; ++k) in[8 + k] = sCE[c * 8 + k];

    float acc[32];
#pragma unroll
    for (int j = 0; j < 32; ++j) acc[j] = sB[j];
#pragma unroll
    for (int k = 0; k < 16; ++k) {
        float v = in[k];
#pragma unroll
        for (int j = 0; j < 32; ++j) acc[j] += sW[j * 16 + k] * v;
    }
    unsigned w[16];
#pragma unroll
    for (int jp = 0; jp < 16; ++jp)
        w[jp] = pk2(fmaxf(acc[2 * jp], 0.f), fmaxf(acc[2 * jp + 1], 0.f));
    uint4* op = (uint4*)(h1 + (size_t)i * 32);
    op[0] = make_uint4(w[0], w[1], w[2], w[3]);
    op[1] = make_uint4(w[4], w[5], w[6], w[7]);
    op[2] = make_uint4(w[8], w[9], w[10], w[11]);
    op[3] = make_uint4(w[12], w[13], w[14], w[15]);
}

// ------------------------------------------------- gather aggregation via CSR
// PARTS threads/node; each owns 8 bf16 channels (16B). f32 accumulate,
// bf16 write. Edge loop unrolled x2 for two gathers in flight.
template <int WIDTH, int PARTS>
__global__ __launch_bounds__(256) void k_agg(
    const int* __restrict__ row_ptr, const int* __restrict__ sorted_src,
    const unsigned short* __restrict__ h, unsigned short* __restrict__ agg, int n)
{
    int tid = blockIdx.x * 256 + threadIdx.x;
    int i = tid / PARTS;
    int p = tid % PARTS;
    if (i >= n) return;
    float a[8] = {0, 0, 0, 0, 0, 0, 0, 0};
    float b[8] = {0, 0, 0, 0, 0, 0, 0, 0};
    int e0 = row_ptr[i], e1 = row_ptr[i + 1];
    const unsigned short* hp = h + p * 8;
    int e = e0;
    for (; e + 2 <= e1; e += 2) {
        int s0 = sorted_src[e];
        int s1 = sorted_src[e + 1];
        uint4 r0 = *(const uint4*)(hp + (size_t)s0 * WIDTH);
        uint4 r1 = *(const uint4*)(hp + (size_t)s1 * WIDTH);
        a[0] += bflo(r0.x); a[1] += bfhi(r0.x); a[2] += bflo(r0.y); a[3] += bfhi(r0.y);
        a[4] += bflo(r0.z); a[5] += bfhi(r0.z); a[6] += bflo(r0.w); a[7] += bfhi(r0.w);
        b[0] += bflo(r1.x); b[1] += bfhi(r1.x); b[2] += bflo(r1.y); b[3] += bfhi(r1.y);
        b[4] += bflo(r1.z); b[5] += bfhi(r1.z); b[6] += bflo(r1.w); b[7] += bfhi(r1.w);
    }
    if (e < e1) {
        int s0 = sorted_src[e];
        uint4 r0 = *(const uint4*)(hp + (size_t)s0 * WIDTH);
        a[0] += bflo(r0.x); a[1] += bfhi(r0.x); a[2] += bflo(r0.y); a[3] += bfhi(r0.y);
        a[4] += bflo(r0.z); a[5] += bfhi(r0.z); a[6] += bflo(r0.w); a[7] += bfhi(r0.w);
    }
#pragma unroll
    for (int q = 0; q < 8; ++q) a[q] += b[q];
    uint4* ap = (uint4*)(agg + (size_t)i * WIDTH + p * 8);
    *ap = make_uint4(pk2(a[0], a[1]), pk2(a[2], a[3]), pk2(a[4], a[5]), pk2(a[6], a[7]));
}

// ---------------------------------------------------- conv (2 nodes/thread)
// Block = 256 thr = 4 waves; wave wq owns output channels [wq*16, wq*16+16).
// Each thread processes 2 nodes (i = blk*128 + nn*64 + lane) -> one LDS b128
// weight read feeds 8 FMAs, at ~90 VGPR (no spill). Clamped loads, guarded
// stores. bf16 in/out, f32 LDS weights + f32 accumulate.
template <int WIN>
__global__ __launch_bounds__(256) void k_conv(
    const unsigned short* __restrict__ agg, const unsigned short* __restrict__ h,
    const float* __restrict__ W_rel, const float* __restrict__ b_rel,
    const float* __restrict__ W_root, unsigned short* __restrict__ out, int n)
{
    __shared__ float sWrel[64 * WIN];
    __shared__ float sWroot[64 * WIN];
    __shared__ float sB[64];
    int t = threadIdx.x;
    for (int i = t; i < 64 * WIN; i += 256) {
        sWrel[i] = W_rel[i];
        sWroot[i] = W_root[i];
    }
    if (t < 64) sB[t] = b_rel[t];
    __syncthreads();

    int lane = t & 63;
    int wq = t >> 6;
    int i0 = blockIdx.x * 128 + lane;        // node 0
    int i1 = i0 + 64;                        // node 1
    int c0 = min(i0, n - 1);
    int c1 = min(i1, n - 1);

    float acc0[16], acc1[16];
#pragma unroll
    for (int j = 0; j < 16; ++j) { acc0[j] = sB[wq * 16 + j]; acc1[j] = acc0[j]; }

    const float* wr = sWrel + (size_t)(wq * 16) * WIN;
    const float* wo = sWroot + (size_t)(wq * 16) * WIN;
    const unsigned short* a0p = agg + (size_t)c0 * WIN;
    const unsigned short* h0p = h + (size_t)c0 * WIN;
    const unsigned short* a1p = agg + (size_t)c1 * WIN;
    const unsigned short* h1p = h + (size_t)c1 * WIN;

#pragma unroll
    for (int kc = 0; kc < WIN / 4; ++kc) {
        uint2 ua0 = *(const uint2*)(a0p + kc * 4);
        uint2 uh0 = *(const uint2*)(h0p + kc * 4);
        uint2 ua1 = *(const uint2*)(a1p + kc * 4);
        uint2 uh1 = *(const uint2*)(h1p + kc * 4);
        float a0[4] = {bflo(ua0.x), bfhi(ua0.x), bflo(ua0.y), bfhi(ua0.y)};
        float g0[4] = {bflo(uh0.x), bfhi(uh0.x), bflo(uh0.y), bfhi(uh0.y)};
        float a1[4] = {bflo(ua1.x), bfhi(ua1.x), bflo(ua1.y), bfhi(ua1.y)};
        float g1[4] = {bflo(uh1.x), bfhi(uh1.x), bflo(uh1.y), bfhi(uh1.y)};
#pragma unroll
        for (int j = 0; j < 16; ++j) {
            float4 w4 = *(const float4*)(wr + (size_t)j * WIN + kc * 4);
            float4 o4 = *(const float4*)(wo + (size_t)j * WIN + kc * 4);
            acc0[j] += w4.x * a0[0] + w4.y * a0[1] + w4.z * a0[2] + w4.w * a0[3]
                     + o4.x * g0[0] + o4.y * g0[1] + o4.z * g0[2] + o4.w * g0[3];
            acc1[j] += w4.x * a1[0] + w4.y * a1[1] + w4.z * a1[2] + w4.w * a1[3]
                     + o4.x * g1[0] + o4.y * g1[1] + o4.z * g1[2] + o4.w * g1[3];
        }
    }

    if (i0 < n) {
        unsigned w[8];
#pragma unroll
        for (int jp = 0; jp < 8; ++jp)
            w[jp] = pk2(fmaxf(acc0[2 * jp], 0.f), fmaxf(acc0[2 * jp + 1], 0.f));
        uint4* op = (uint4*)(out + (size_t)i0 * 64 + wq * 16);
        op[0] = make_uint4(w[0], w[1], w[2], w[3]);
        op[1] = make_uint4(w[4], w[5], w[6], w[7]);
    }
    if (i1 < n) {
        unsigned w[8];
#pragma unroll
        for (int jp = 0; jp < 8; ++jp)
            w[jp] = pk2(fmaxf(acc1[2 * jp], 0.f), fmaxf(acc1[2 * jp + 1], 0.f));
        uint4* op = (uint4*)(out + (size_t)i1 * 64 + wq * 16);
        op[0] = make_uint4(w[0], w[1], w[2], w[3]);
        op[1] = make_uint4(w[4], w[5], w[6], w[7]);
    }
}

// ------------------------------------------- pool (block per graph) + classifier
__global__ __launch_bounds__(256) void k_pool_cls(
    const unsigned short* __restrict__ h3, const int* __restrict__ batch,
    const float* __restrict__ W_cls, const float* __restrict__ b_cls,
    float* __restrict__ out, int n)
{
    __shared__ float part[4][64];
    __shared__ float pool[64];
    __shared__ int range[2];
    int g = blockIdx.x;
    int t = threadIdx.x;

    if (t < 2) {
        int key = g + t;
        int lo = 0, hi = n;
        while (lo < hi) {
            int mid = (lo + hi) >> 1;
            if (batch[mid] < key) lo = mid + 1; else hi = mid;
        }
        range[t] = lo;
    }
    __syncthreads();
    int start = range[0], end = range[1];

    int j = t & 63;
    int sub = t >> 6;
    float local = 0.f;
    for (int i = start + sub; i < end; i += 4) {
        unsigned short u = h3[(size_t)i * 64 + j];
        local += bflo((unsigned)u);
    }
    part[sub][j] = local;
    __syncthreads();

    if (t < 64) {
        float cnt = (float)(end - start);
        float inv = 1.0f / fmaxf(cnt, 1.0f);
        pool[t] = (part[0][t] + part[1][t] + part[2][t] + part[3][t]) * inv;
    }
    __syncthreads();

    if (t < 10) {
        float acc = b_cls[t];
#pragma unroll
        for (int k = 0; k < 64; ++k) acc += W_cls[t * 64 + k] * pool[k];
        out[(size_t)g * 10 + t] = acc;
    }
}

// ---------------------------------------------------------------- launch
extern "C" void kernel_launch(void* const* d_in, const int* in_sizes, int n_in,
                              void* d_out, int out_size, void* d_ws, size_t ws_size,
                              hipStream_t stream)
{
    const int* x        = (const int*)d_in[0];
    const int* ei       = (const int*)d_in[1];
    const int* batch    = (const int*)d_in[2];
    const float* shape_emb = (const float*)d_in[4];
    const float* color_emb = (const float*)d_in[5];
    const float* W_pre   = (const float*)d_in[6];
    const float* b_pre   = (const float*)d_in[7];
    const float* W_rel1  = (const float*)d_in[8];
    const float* b_rel1  = (const float*)d_in[9];
    const float* W_root1 = (const float*)d_in[10];
    const float* W_rel2  = (const float*)d_in[11];
    const float* b_rel2  = (const float*)d_in[12];
    const float* W_root2 = (const float*)d_in[13];
    const float* W_cls   = (const float*)d_in[14];
    const float* b_cls   = (const float*)d_in[15];

    const int n  = in_sizes[0] / 2;   // 100000
    const int nE = in_sizes[1] / 2;   // 1200000
    const int G  = NGRAPHS;
    const int* src = ei;
    const int* dst = ei + nE;

    // workspace: bf16 buffers then ints, all disjoint.
    unsigned short* us = (unsigned short*)d_ws;
    unsigned short* h1B   = us;                         // N*32
    unsigned short* agg1B = h1B + (size_t)n * 32;       // N*32
    unsigned short* h2B   = agg1B + (size_t)n * 32;     // N*64
    unsigned short* agg2B = h2B + (size_t)n * 64;       // N*64
    unsigned short* h3B   = agg2B + (size_t)n * 64;     // N*64
    int* ints       = (int*)(h3B + (size_t)n * 64);
    int* row_ptr    = ints;
    int* hist       = ints + (n + 1);
    int* cursor     = ints + (n + 1) + n;
    int* sorted_src = ints + (n + 1) + 2 * n;
    int* bsum       = sorted_src + nE;
    int* boffs      = bsum + 64;

    const int EB = (nE + 255) / 256;
    const int NB = (n + 255) / 256;
    const int CB = (n + 127) / 128;  // conv: 128 nodes/block
    const int SB = (n + SCAN_CHUNK - 1) / SCAN_CHUNK;

    // --- CSR build ---
    hipMemsetAsync(hist, 0, (size_t)n * sizeof(int), stream);
    k_hist<<<EB, 256, 0, stream>>>(dst, hist, nE);
    k_scan_part<<<SB, 256, 0, stream>>>(hist, bsum, n);
    k_scan_mid<<<1, 64, 0, stream>>>(bsum, boffs, row_ptr, SB, n);
    k_scan_apply<<<SB, 256, 0, stream>>>(hist, boffs, row_ptr, cursor, n);
    k_scatteridx<<<EB, 256, 0, stream>>>(src, dst, cursor, sorted_src, nE);

    // --- forward ---
    k_pre<<<NB, 256, 0, stream>>>(x, shape_emb, color_emb, W_pre, b_pre, h1B, n);
    k_agg<32, 4><<<((size_t)n * 4 + 255) / 256, 256, 0, stream>>>(row_ptr, sorted_src, h1B, agg1B, n);
    k_conv<32><<<CB, 256, 0, stream>>>(agg1B, h1B, W_rel1, b_rel1, W_root1, h2B, n);
    k_agg<64, 8><<<((size_t)n * 8 + 255) / 256, 256, 0, stream>>>(row_ptr, sorted_src, h2B, agg2B, n);
    k_conv<64><<<CB, 256, 0, stream>>>(agg2B, h2B, W_rel2, b_rel2, W_root2, h3B, n);
    k_pool_cls<<<G, 256, 0, stream>>>(h3B, batch, W_cls, b_cls, (float*)d_out, n);
}

// Round 7
// 352.442 us; speedup vs baseline: 8.5613x; 6.3968x over previous
//
#include <hip/hip_runtime.h>
#include <hip/hip_bf16.h>

// SPRGNN: 2-layer GraphConv GNN forward. CSR-gather, f16 activation storage,
// MFMA conv, f32 accumulate. N=100000, E=1200000, G=1000.
//
// R7: conv via mfma_f32_16x16x32_f16 (R4 scalar conv was LDS-pipe bound at
// 126us; R5/R6 wider scalar variants spilled to 256 VGPR + GBs of scratch).
// Weights live in B-fragments in registers (loaded once per block, sched-
// barrier-fenced to bound liveness); activations stream as A-fragments.
// Activations stored f16 (same bytes as bf16, 4x finer mantissa).

#define NGRAPHS 1000
#define SCAN_CHUNK 4096

typedef _Float16 f16x8 __attribute__((ext_vector_type(8)));
typedef float f32x4 __attribute__((ext_vector_type(4)));

// ---------------------------------------------------------------- CSR build
__global__ __launch_bounds__(256) void k_hist(const int* __restrict__ dst,
                                              int* __restrict__ hist, int nE)
{
    int e = blockIdx.x * 256 + threadIdx.x;
    if (e < nE) atomicAdd(&hist[dst[e]], 1);
}

__global__ __launch_bounds__(256) void k_scan_part(const int* __restrict__ hist,
                                                   int* __restrict__ bsum, int n)
{
    __shared__ int s[256];
    int t = threadIdx.x;
    int beg = blockIdx.x * SCAN_CHUNK + t * 16;
    int sum = 0;
#pragma unroll
    for (int q = 0; q < 16; ++q) {
        int i = beg + q;
        if (i < n) sum += hist[i];
    }
    s[t] = sum;
    __syncthreads();
    for (int off = 128; off > 0; off >>= 1) {
        if (t < off) s[t] += s[t + off];
        __syncthreads();
    }
    if (t == 0) bsum[blockIdx.x] = s[0];
}

__global__ __launch_bounds__(64) void k_scan_mid(const int* __restrict__ bsum,
                                                 int* __restrict__ boffs,
                                                 int* __restrict__ row_ptr,
                                                 int B, int n)
{
    if (threadIdx.x == 0) {
        int run = 0;
        for (int b = 0; b < B; ++b) {
            boffs[b] = run;
            run += bsum[b];
        }
        row_ptr[n] = run;
    }
}

__global__ __launch_bounds__(256) void k_scan_apply(const int* __restrict__ hist,
                                                    const int* __restrict__ boffs,
                                                    int* __restrict__ row_ptr,
                                                    int* __restrict__ cursor, int n)
{
    __shared__ int s[256];
    int t = threadIdx.x;
    int beg = blockIdx.x * SCAN_CHUNK + t * 16;
    int v[16];
    int sum = 0;
#pragma unroll
    for (int q = 0; q < 16; ++q) {
        int i = beg + q;
        v[q] = (i < n) ? hist[i] : 0;
        sum += v[q];
    }
    s[t] = sum;
    __syncthreads();
    for (int off = 1; off < 256; off <<= 1) {
        int x = (t >= off) ? s[t - off] : 0;
        __syncthreads();
        s[t] += x;
        __syncthreads();
    }
    int base = boffs[blockIdx.x] + ((t == 0) ? 0 : s[t - 1]);
#pragma unroll
    for (int q = 0; q < 16; ++q) {
        int i = beg + q;
        if (i < n) {
            row_ptr[i] = base;
            cursor[i] = base;
            base += v[q];
        }
    }
}

__global__ __launch_bounds__(256) void k_scatteridx(
    const int* __restrict__ src, const int* __restrict__ dst,
    int* __restrict__ cursor, int* __restrict__ sorted_src, int nE)
{
    int e = blockIdx.x * 256 + threadIdx.x;
    if (e >= nE) return;
    int pos = atomicAdd(&cursor[dst[e]], 1);
    sorted_src[pos] = src[e];
}

// ---------------------------------------------------------------- K1: pre-MLP
__global__ __launch_bounds__(256) void k_pre(
    const int* __restrict__ x,
    const float* __restrict__ shape_emb, const float* __restrict__ color_emb,
    const float* __restrict__ W_pre, const float* __restrict__ b_pre,
    _Float16* __restrict__ h1, int n)
{
    __shared__ float sW[32 * 16];
    __shared__ float sB[32];
    __shared__ float sSE[16 * 8];
    __shared__ float sCE[8 * 8];
    int t = threadIdx.x;
    for (int i = t; i < 32 * 16; i += 256) sW[i] = W_pre[i];
    if (t < 32) sB[t] = b_pre[t];
    for (int i = t; i < 16 * 8; i += 256) sSE[i] = shape_emb[i];
    if (t < 64) sCE[t] = color_emb[t];
    __syncthreads();

    int i = blockIdx.x * 256 + t;
    if (i >= n) return;
    int s = x[2 * i];
    int c = x[2 * i + 1];
    float in[16];
#pragma unroll
    for (int k = 0; k < 8; ++k) in[k] = sSE[s * 8 + k];
#pragma unroll
    for (int k = 0; k < 8; ++k) in[8 + k] = sCE[c * 8 + k];

    float acc[32];
#pragma unroll
    for (int j = 0; j < 32; ++j) acc[j] = sB[j];
#pragma unroll
    for (int k = 0; k < 16; ++k) {
        float v = in[k];
#pragma unroll
        for (int j = 0; j < 32; ++j) acc[j] += sW[j * 16 + k] * v;
    }
#pragma unroll
    for (int g = 0; g < 4; ++g) {
        f16x8 o;
#pragma unroll
        for (int q = 0; q < 8; ++q) o[q] = (_Float16)fmaxf(acc[g * 8 + q], 0.f);
        *(f16x8*)(h1 + (size_t)i * 32 + g * 8) = o;
    }
}

// ------------------------------------------------- gather aggregation via CSR
// PARTS threads/node; each owns 8 f16 channels (16B). f32 accumulate, f16 out.
template <int WIDTH, int PARTS>
__global__ __launch_bounds__(256) void k_agg(
    const int* __restrict__ row_ptr, const int* __restrict__ sorted_src,
    const _Float16* __restrict__ h, _Float16* __restrict__ agg, int n)
{
    int tid = blockIdx.x * 256 + threadIdx.x;
    int i = tid / PARTS;
    int p = tid % PARTS;
    if (i >= n) return;
    float a[8] = {0, 0, 0, 0, 0, 0, 0, 0};
    float b[8] = {0, 0, 0, 0, 0, 0, 0, 0};
    int e0 = row_ptr[i], e1 = row_ptr[i + 1];
    const _Float16* hp = h + p * 8;
    int e = e0;
    for (; e + 2 <= e1; e += 2) {
        int s0 = sorted_src[e];
        int s1 = sorted_src[e + 1];
        f16x8 r0 = *(const f16x8*)(hp + (size_t)s0 * WIDTH);
        f16x8 r1 = *(const f16x8*)(hp + (size_t)s1 * WIDTH);
#pragma unroll
        for (int q = 0; q < 8; ++q) { a[q] += (float)r0[q]; b[q] += (float)r1[q]; }
    }
    if (e < e1) {
        int s0 = sorted_src[e];
        f16x8 r0 = *(const f16x8*)(hp + (size_t)s0 * WIDTH);
#pragma unroll
        for (int q = 0; q < 8; ++q) a[q] += (float)r0[q];
    }
    f16x8 o;
#pragma unroll
    for (int q = 0; q < 8; ++q) o[q] = (_Float16)(a[q] + b[q]);
    *(f16x8*)(agg + (size_t)i * WIDTH + p * 8) = o;
}

// ---------------------------------------------------- conv via MFMA
// out[i][j] = relu(b[j] + sum_k Wrel[j][k] agg[i][k] + Wroot[j][k] h[i][k])
// GEMM: [agg | h] [N, 2W] @ B [2W, 64], mfma_f32_16x16x32_f16.
// Block = 256 thr = 4 waves; wave = 32 nodes x 64 ch (2 node-tiles x 4
// ch-tiles). B-fragments in registers, built once (sched_barrier-fenced).
// A-frag: row = lane&15, k = (lane>>4)*8+e (16B vector load).
// D: col = lane&15, row = (lane>>4)*4 + reg.
template <int WIN>
__global__ __launch_bounds__(256) void k_conv_mfma(
    const _Float16* __restrict__ agg, const _Float16* __restrict__ h,
    const float* __restrict__ W_rel, const float* __restrict__ b_rel,
    const float* __restrict__ W_root, _Float16* __restrict__ out, int n)
{
    constexpr int NK = (2 * WIN) / 32;   // K-steps: conv32 -> 2, conv64 -> 4
    int t = threadIdx.x;
    int lane = t & 63;
    int w = t >> 6;
    int col = lane & 15;
    int krow = lane >> 4;                 // 0..3

    // ---- B fragments (weights), once per block ----
    f16x8 B[NK][4];
#pragma unroll
    for (int ks = 0; ks < NK; ++ks) {
#pragma unroll
        for (int ct = 0; ct < 4; ++ct) {
            int j = ct * 16 + col;
            int kb = ks * 32 + krow * 8;
            const float* srcw = (ks < NK / 2)
                ? (W_rel + (size_t)j * WIN + kb)
                : (W_root + (size_t)j * WIN + (kb - WIN));
            float4 w0 = *(const float4*)(srcw);
            float4 w1 = *(const float4*)(srcw + 4);
            f16x8 bb;
            bb[0] = (_Float16)w0.x; bb[1] = (_Float16)w0.y;
            bb[2] = (_Float16)w0.z; bb[3] = (_Float16)w0.w;
            bb[4] = (_Float16)w1.x; bb[5] = (_Float16)w1.y;
            bb[6] = (_Float16)w1.z; bb[7] = (_Float16)w1.w;
            B[ks][ct] = bb;
        }
        __builtin_amdgcn_sched_barrier(0);  // bound load-hoisting liveness
    }

    float bias[4];
#pragma unroll
    for (int ct = 0; ct < 4; ++ct) bias[ct] = b_rel[ct * 16 + col];

    int nodebase = blockIdx.x * 128 + w * 32;

    f32x4 acc[2][4];
#pragma unroll
    for (int nt = 0; nt < 2; ++nt)
#pragma unroll
        for (int ct = 0; ct < 4; ++ct) acc[nt][ct] = (f32x4){0.f, 0.f, 0.f, 0.f};

#pragma unroll
    for (int ks = 0; ks < NK; ++ks) {
        const _Float16* base = (ks < NK / 2) ? agg : h;
        int koff = ((ks < NK / 2) ? ks : ks - NK / 2) * 32 + krow * 8;
#pragma unroll
        for (int nt = 0; nt < 2; ++nt) {
            int i = nodebase + nt * 16 + col;
            i = min(i, n - 1);
            f16x8 a = *(const f16x8*)(base + (size_t)i * WIN + koff);
#pragma unroll
            for (int ct = 0; ct < 4; ++ct)
                acc[nt][ct] = __builtin_amdgcn_mfma_f32_16x16x32_f16(
                    a, B[ks][ct], acc[nt][ct], 0, 0, 0);
        }
    }

    // ---- epilogue: bias + relu + f16 store ----
#pragma unroll
    for (int nt = 0; nt < 2; ++nt) {
#pragma unroll
        for (int r = 0; r < 4; ++r) {
            int node = nodebase + nt * 16 + krow * 4 + r;
            if (node < n) {
#pragma unroll
                for (int ct = 0; ct < 4; ++ct) {
                    float v = acc[nt][ct][r] + bias[ct];
                    out[(size_t)node * 64 + ct * 16 + col] = (_Float16)fmaxf(v, 0.f);
                }
            }
        }
    }
}

// ------------------------------------------- pool (block per graph) + classifier
__global__ __launch_bounds__(256) void k_pool_cls(
    const _Float16* __restrict__ h3, const int* __restrict__ batch,
    const float* __restrict__ W_cls, const float* __restrict__ b_cls,
    float* __restrict__ out, int n)
{
    __shared__ float part[4][64];
    __shared__ float pool[64];
    __shared__ int range[2];
    int g = blockIdx.x;
    int t = threadIdx.x;

    if (t < 2) {
        int key = g + t;
        int lo = 0, hi = n;
        while (lo < hi) {
            int mid = (lo + hi) >> 1;
            if (batch[mid] < key) lo = mid + 1; else hi = mid;
        }
        range[t] = lo;
    }
    __syncthreads();
    int start = range[0], end = range[1];

    int j = t & 63;
    int sub = t >> 6;
    float local = 0.f;
    for (int i = start + sub; i < end; i += 4)
        local += (float)h3[(size_t)i * 64 + j];
    part[sub][j] = local;
    __syncthreads();

    if (t < 64) {
        float cnt = (float)(end - start);
        float inv = 1.0f / fmaxf(cnt, 1.0f);
        pool[t] = (part[0][t] + part[1][t] + part[2][t] + part[3][t]) * inv;
    }
    __syncthreads();

    if (t < 10) {
        float acc = b_cls[t];
#pragma unroll
        for (int k = 0; k < 64; ++k) acc += W_cls[t * 64 + k] * pool[k];
        out[(size_t)g * 10 + t] = acc;
    }
}

// ---------------------------------------------------------------- launch
extern "C" void kernel_launch(void* const* d_in, const int* in_sizes, int n_in,
                              void* d_out, int out_size, void* d_ws, size_t ws_size,
                              hipStream_t stream)
{
    const int* x        = (const int*)d_in[0];
    const int* ei       = (const int*)d_in[1];
    const int* batch    = (const int*)d_in[2];
    const float* shape_emb = (const float*)d_in[4];
    const float* color_emb = (const float*)d_in[5];
    const float* W_pre   = (const float*)d_in[6];
    const float* b_pre   = (const float*)d_in[7];
    const float* W_rel1  = (const float*)d_in[8];
    const float* b_rel1  = (const float*)d_in[9];
    const float* W_root1 = (const float*)d_in[10];
    const float* W_rel2  = (const float*)d_in[11];
    const float* b_rel2  = (const float*)d_in[12];
    const float* W_root2 = (const float*)d_in[13];
    const float* W_cls   = (const float*)d_in[14];
    const float* b_cls   = (const float*)d_in[15];

    const int n  = in_sizes[0] / 2;   // 100000
    const int nE = in_sizes[1] / 2;   // 1200000
    const int G  = NGRAPHS;
    const int* src = ei;
    const int* dst = ei + nE;

    // workspace: f16 buffers then ints, all disjoint.
    _Float16* us = (_Float16*)d_ws;
    _Float16* h1B   = us;                         // N*32
    _Float16* agg1B = h1B + (size_t)n * 32;       // N*32
    _Float16* h2B   = agg1B + (size_t)n * 32;     // N*64
    _Float16* agg2B = h2B + (size_t)n * 64;       // N*64
    _Float16* h3B   = agg2B + (size_t)n * 64;     // N*64
    int* ints       = (int*)(h3B + (size_t)n * 64);
    int* row_ptr    = ints;
    int* hist       = ints + (n + 1);
    int* cursor     = ints + (n + 1) + n;
    int* sorted_src = ints + (n + 1) + 2 * n;
    int* bsum       = sorted_src + nE;
    int* boffs      = bsum + 64;

    const int EB = (nE + 255) / 256;
    const int NB = (n + 255) / 256;
    const int CB = (n + 127) / 128;  // conv: 128 nodes/block
    const int SB = (n + SCAN_CHUNK - 1) / SCAN_CHUNK;

    // --- CSR build ---
    hipMemsetAsync(hist, 0, (size_t)n * sizeof(int), stream);
    k_hist<<<EB, 256, 0, stream>>>(dst, hist, nE);
    k_scan_part<<<SB, 256, 0, stream>>>(hist, bsum, n);
    k_scan_mid<<<1, 64, 0, stream>>>(bsum, boffs, row_ptr, SB, n);
    k_scan_apply<<<SB, 256, 0, stream>>>(hist, boffs, row_ptr, cursor, n);
    k_scatteridx<<<EB, 256, 0, stream>>>(src, dst, cursor, sorted_src, nE);

    // --- forward ---
    k_pre<<<NB, 256, 0, stream>>>(x, shape_emb, color_emb, W_pre, b_pre, h1B, n);
    k_agg<32, 4><<<((size_t)n * 4 + 255) / 256, 256, 0, stream>>>(row_ptr, sorted_src, h1B, agg1B, n);
    k_conv_mfma<32><<<CB, 256, 0, stream>>>(agg1B, h1B, W_rel1, b_rel1, W_root1, h2B, n);
    k_agg<64, 8><<<((size_t)n * 8 + 255) / 256, 256, 0, stream>>>(row_ptr, sorted_src, h2B, agg2B, n);
    k_conv_mfma<64><<<CB, 256, 0, stream>>>(agg2B, h2B, W_rel2, b_rel2, W_root2, h3B, n);
    k_pool_cls<<<G, 256, 0, stream>>>(h3B, batch, W_cls, b_cls, (float*)d_out, n);
}

// Round 8
// 273.673 us; speedup vs baseline: 11.0255x; 1.2878x over previous
//
#include <hip/hip_runtime.h>
#include <hip/hip_bf16.h>

// SPRGNN: 2-layer GraphConv GNN forward. CSR-gather, f16 activation storage,
// MFMA conv, f32 accumulate. N=100000, E=1200000, G=1000.
//
// R8: (a) rank-based CSR scatter: k_hist keeps atomicAdd's return as rank[e],
// k_scatteridx becomes atomic-free (R7: 90us, 83MB write-amp + 1.2M atomics).
// (b) agg edge loop unrolled x4 for deeper MLP. (c) h3 reuses h1+agg1 region
// so rank[E] fits in prior workspace footprint.

#define NGRAPHS 1000
#define SCAN_CHUNK 4096

typedef _Float16 f16x8 __attribute__((ext_vector_type(8)));
typedef float f32x4 __attribute__((ext_vector_type(4)));

// ---------------------------------------------------------------- CSR build
// pass 1: histogram of dst; atomicAdd's old value = edge's rank within its dst
__global__ __launch_bounds__(256) void k_hist(const int* __restrict__ dst,
                                              int* __restrict__ hist,
                                              int* __restrict__ rank, int nE)
{
    int e = blockIdx.x * 256 + threadIdx.x;
    if (e < nE) rank[e] = atomicAdd(&hist[dst[e]], 1);
}

__global__ __launch_bounds__(256) void k_scan_part(const int* __restrict__ hist,
                                                   int* __restrict__ bsum, int n)
{
    __shared__ int s[256];
    int t = threadIdx.x;
    int beg = blockIdx.x * SCAN_CHUNK + t * 16;
    int sum = 0;
#pragma unroll
    for (int q = 0; q < 16; ++q) {
        int i = beg + q;
        if (i < n) sum += hist[i];
    }
    s[t] = sum;
    __syncthreads();
    for (int off = 128; off > 0; off >>= 1) {
        if (t < off) s[t] += s[t + off];
        __syncthreads();
    }
    if (t == 0) bsum[blockIdx.x] = s[0];
}

__global__ __launch_bounds__(64) void k_scan_mid(const int* __restrict__ bsum,
                                                 int* __restrict__ boffs,
                                                 int* __restrict__ row_ptr,
                                                 int B, int n)
{
    if (threadIdx.x == 0) {
        int run = 0;
        for (int b = 0; b < B; ++b) {
            boffs[b] = run;
            run += bsum[b];
        }
        row_ptr[n] = run;
    }
}

__global__ __launch_bounds__(256) void k_scan_apply(const int* __restrict__ hist,
                                                    const int* __restrict__ boffs,
                                                    int* __restrict__ row_ptr, int n)
{
    __shared__ int s[256];
    int t = threadIdx.x;
    int beg = blockIdx.x * SCAN_CHUNK + t * 16;
    int v[16];
    int sum = 0;
#pragma unroll
    for (int q = 0; q < 16; ++q) {
        int i = beg + q;
        v[q] = (i < n) ? hist[i] : 0;
        sum += v[q];
    }
    s[t] = sum;
    __syncthreads();
    for (int off = 1; off < 256; off <<= 1) {
        int x = (t >= off) ? s[t - off] : 0;
        __syncthreads();
        s[t] += x;
        __syncthreads();
    }
    int base = boffs[blockIdx.x] + ((t == 0) ? 0 : s[t - 1]);
#pragma unroll
    for (int q = 0; q < 16; ++q) {
        int i = beg + q;
        if (i < n) {
            row_ptr[i] = base;
            base += v[q];
        }
    }
}

// pass 2: atomic-free scatter using row_ptr + rank
__global__ __launch_bounds__(256) void k_scatteridx(
    const int* __restrict__ src, const int* __restrict__ dst,
    const int* __restrict__ row_ptr, const int* __restrict__ rank,
    int* __restrict__ sorted_src, int nE)
{
    int e = blockIdx.x * 256 + threadIdx.x;
    if (e >= nE) return;
    int d = dst[e];
    sorted_src[row_ptr[d] + rank[e]] = src[e];
}

// ---------------------------------------------------------------- K1: pre-MLP
__global__ __launch_bounds__(256) void k_pre(
    const int* __restrict__ x,
    const float* __restrict__ shape_emb, const float* __restrict__ color_emb,
    const float* __restrict__ W_pre, const float* __restrict__ b_pre,
    _Float16* __restrict__ h1, int n)
{
    __shared__ float sW[32 * 16];
    __shared__ float sB[32];
    __shared__ float sSE[16 * 8];
    __shared__ float sCE[8 * 8];
    int t = threadIdx.x;
    for (int i = t; i < 32 * 16; i += 256) sW[i] = W_pre[i];
    if (t < 32) sB[t] = b_pre[t];
    for (int i = t; i < 16 * 8; i += 256) sSE[i] = shape_emb[i];
    if (t < 64) sCE[t] = color_emb[t];
    __syncthreads();

    int i = blockIdx.x * 256 + t;
    if (i >= n) return;
    int s = x[2 * i];
    int c = x[2 * i + 1];
    float in[16];
#pragma unroll
    for (int k = 0; k < 8; ++k) in[k] = sSE[s * 8 + k];
#pragma unroll
    for (int k = 0; k < 8; ++k) in[8 + k] = sCE[c * 8 + k];

    float acc[32];
#pragma unroll
    for (int j = 0; j < 32; ++j) acc[j] = sB[j];
#pragma unroll
    for (int k = 0; k < 16; ++k) {
        float v = in[k];
#pragma unroll
        for (int j = 0; j < 32; ++j) acc[j] += sW[j * 16 + k] * v;
    }
#pragma unroll
    for (int g = 0; g < 4; ++g) {
        f16x8 o;
#pragma unroll
        for (int q = 0; q < 8; ++q) o[q] = (_Float16)fmaxf(acc[g * 8 + q], 0.f);
        *(f16x8*)(h1 + (size_t)i * 32 + g * 8) = o;
    }
}

// ------------------------------------------------- gather aggregation via CSR
// PARTS threads/node; each owns 8 f16 channels (16B). f32 accumulate, f16 out.
// Edge loop unrolled x4 for four gathers in flight (avg degree ~12).
template <int WIDTH, int PARTS>
__global__ __launch_bounds__(256) void k_agg(
    const int* __restrict__ row_ptr, const int* __restrict__ sorted_src,
    const _Float16* __restrict__ h, _Float16* __restrict__ agg, int n)
{
    int tid = blockIdx.x * 256 + threadIdx.x;
    int i = tid / PARTS;
    int p = tid % PARTS;
    if (i >= n) return;
    float a[8] = {0, 0, 0, 0, 0, 0, 0, 0};
    float b[8] = {0, 0, 0, 0, 0, 0, 0, 0};
    int e0 = row_ptr[i], e1 = row_ptr[i + 1];
    const _Float16* hp = h + p * 8;
    int e = e0;
    for (; e + 4 <= e1; e += 4) {
        int s0 = sorted_src[e];
        int s1 = sorted_src[e + 1];
        int s2 = sorted_src[e + 2];
        int s3 = sorted_src[e + 3];
        f16x8 r0 = *(const f16x8*)(hp + (size_t)s0 * WIDTH);
        f16x8 r1 = *(const f16x8*)(hp + (size_t)s1 * WIDTH);
        f16x8 r2 = *(const f16x8*)(hp + (size_t)s2 * WIDTH);
        f16x8 r3 = *(const f16x8*)(hp + (size_t)s3 * WIDTH);
#pragma unroll
        for (int q = 0; q < 8; ++q) {
            a[q] += (float)r0[q] + (float)r2[q];
            b[q] += (float)r1[q] + (float)r3[q];
        }
    }
    for (; e < e1; ++e) {
        int s0 = sorted_src[e];
        f16x8 r0 = *(const f16x8*)(hp + (size_t)s0 * WIDTH);
#pragma unroll
        for (int q = 0; q < 8; ++q) a[q] += (float)r0[q];
    }
    f16x8 o;
#pragma unroll
    for (int q = 0; q < 8; ++q) o[q] = (_Float16)(a[q] + b[q]);
    *(f16x8*)(agg + (size_t)i * WIDTH + p * 8) = o;
}

// ---------------------------------------------------- conv via MFMA
// out[i][j] = relu(b[j] + sum_k Wrel[j][k] agg[i][k] + Wroot[j][k] h[i][k])
// GEMM: [agg | h] [N, 2W] @ B [2W, 64], mfma_f32_16x16x32_f16.
// Block = 256 thr = 4 waves; wave = 32 nodes x 64 ch. B-fragments in
// registers, built once (sched_barrier-fenced).
template <int WIN>
__global__ __launch_bounds__(256) void k_conv_mfma(
    const _Float16* __restrict__ agg, const _Float16* __restrict__ h,
    const float* __restrict__ W_rel, const float* __restrict__ b_rel,
    const float* __restrict__ W_root, _Float16* __restrict__ out, int n)
{
    constexpr int NK = (2 * WIN) / 32;   // K-steps: conv32 -> 2, conv64 -> 4
    int t = threadIdx.x;
    int lane = t & 63;
    int w = t >> 6;
    int col = lane & 15;
    int krow = lane >> 4;                 // 0..3

    // ---- B fragments (weights), once per block ----
    f16x8 B[NK][4];
#pragma unroll
    for (int ks = 0; ks < NK; ++ks) {
#pragma unroll
        for (int ct = 0; ct < 4; ++ct) {
            int j = ct * 16 + col;
            int kb = ks * 32 + krow * 8;
            const float* srcw = (ks < NK / 2)
                ? (W_rel + (size_t)j * WIN + kb)
                : (W_root + (size_t)j * WIN + (kb - WIN));
            float4 w0 = *(const float4*)(srcw);
            float4 w1 = *(const float4*)(srcw + 4);
            f16x8 bb;
            bb[0] = (_Float16)w0.x; bb[1] = (_Float16)w0.y;
            bb[2] = (_Float16)w0.z; bb[3] = (_Float16)w0.w;
            bb[4] = (_Float16)w1.x; bb[5] = (_Float16)w1.y;
            bb[6] = (_Float16)w1.z; bb[7] = (_Float16)w1.w;
            B[ks][ct] = bb;
        }
        __builtin_amdgcn_sched_barrier(0);  // bound load-hoisting liveness
    }

    float bias[4];
#pragma unroll
    for (int ct = 0; ct < 4; ++ct) bias[ct] = b_rel[ct * 16 + col];

    int nodebase = blockIdx.x * 128 + w * 32;

    f32x4 acc[2][4];
#pragma unroll
    for (int nt = 0; nt < 2; ++nt)
#pragma unroll
        for (int ct = 0; ct < 4; ++ct) acc[nt][ct] = (f32x4){0.f, 0.f, 0.f, 0.f};

#pragma unroll
    for (int ks = 0; ks < NK; ++ks) {
        const _Float16* base = (ks < NK / 2) ? agg : h;
        int koff = ((ks < NK / 2) ? ks : ks - NK / 2) * 32 + krow * 8;
#pragma unroll
        for (int nt = 0; nt < 2; ++nt) {
            int i = nodebase + nt * 16 + col;
            i = min(i, n - 1);
            f16x8 a = *(const f16x8*)(base + (size_t)i * WIN + koff);
#pragma unroll
            for (int ct = 0; ct < 4; ++ct)
                acc[nt][ct] = __builtin_amdgcn_mfma_f32_16x16x32_f16(
                    a, B[ks][ct], acc[nt][ct], 0, 0, 0);
        }
    }

    // ---- epilogue: bias + relu + f16 store ----
#pragma unroll
    for (int nt = 0; nt < 2; ++nt) {
#pragma unroll
        for (int r = 0; r < 4; ++r) {
            int node = nodebase + nt * 16 + krow * 4 + r;
            if (node < n) {
#pragma unroll
                for (int ct = 0; ct < 4; ++ct) {
                    float v = acc[nt][ct][r] + bias[ct];
                    out[(size_t)node * 64 + ct * 16 + col] = (_Float16)fmaxf(v, 0.f);
                }
            }
        }
    }
}

// ------------------------------------------- pool (block per graph) + classifier
__global__ __launch_bounds__(256) void k_pool_cls(
    const _Float16* __restrict__ h3, const int* __restrict__ batch,
    const float* __restrict__ W_cls, const float* __restrict__ b_cls,
    float* __restrict__ out, int n)
{
    __shared__ float part[4][64];
    __shared__ float pool[64];
    __shared__ int range[2];
    int g = blockIdx.x;
    int t = threadIdx.x;

    if (t < 2) {
        int key = g + t;
        int lo = 0, hi = n;
        while (lo < hi) {
            int mid = (lo + hi) >> 1;
            if (batch[mid] < key) lo = mid + 1; else hi = mid;
        }
        range[t] = lo;
    }
    __syncthreads();
    int start = range[0], end = range[1];

    int j = t & 63;
    int sub = t >> 6;
    float local = 0.f;
    for (int i = start + sub; i < end; i += 4)
        local += (float)h3[(size_t)i * 64 + j];
    part[sub][j] = local;
    __syncthreads();

    if (t < 64) {
        float cnt = (float)(end - start);
        float inv = 1.0f / fmaxf(cnt, 1.0f);
        pool[t] = (part[0][t] + part[1][t] + part[2][t] + part[3][t]) * inv;
    }
    __syncthreads();

    if (t < 10) {
        float acc = b_cls[t];
#pragma unroll
        for (int k = 0; k < 64; ++k) acc += W_cls[t * 64 + k] * pool[k];
        out[(size_t)g * 10 + t] = acc;
    }
}

// ---------------------------------------------------------------- launch
extern "C" void kernel_launch(void* const* d_in, const int* in_sizes, int n_in,
                              void* d_out, int out_size, void* d_ws, size_t ws_size,
                              hipStream_t stream)
{
    const int* x        = (const int*)d_in[0];
    const int* ei       = (const int*)d_in[1];
    const int* batch    = (const int*)d_in[2];
    const float* shape_emb = (const float*)d_in[4];
    const float* color_emb = (const float*)d_in[5];
    const float* W_pre   = (const float*)d_in[6];
    const float* b_pre   = (const float*)d_in[7];
    const float* W_rel1  = (const float*)d_in[8];
    const float* b_rel1  = (const float*)d_in[9];
    const float* W_root1 = (const float*)d_in[10];
    const float* W_rel2  = (const float*)d_in[11];
    const float* b_rel2  = (const float*)d_in[12];
    const float* W_root2 = (const float*)d_in[13];
    const float* W_cls   = (const float*)d_in[14];
    const float* b_cls   = (const float*)d_in[15];

    const int n  = in_sizes[0] / 2;   // 100000
    const int nE = in_sizes[1] / 2;   // 1200000
    const int G  = NGRAPHS;
    const int* src = ei;
    const int* dst = ei + nE;

    // workspace (f16 elements):
    //  [0,      n*32)  h1B      -- dead after conv1
    //  [n*32,   n*64)  agg1B    -- dead after conv1
    //  [n*64,   n*128) h2B
    //  [n*128,  n*192) agg2B
    //  h3B = [0, n*64)  (reuses h1B+agg1B)
    //  ints after n*192: row_ptr[n+1] | hist[n] | rank[E] | sorted_src[E] | bsum | boffs
    _Float16* us = (_Float16*)d_ws;
    _Float16* h1B   = us;
    _Float16* agg1B = h1B + (size_t)n * 32;
    _Float16* h2B   = us + (size_t)n * 64;
    _Float16* agg2B = us + (size_t)n * 128;
    _Float16* h3B   = us;  // reuse h1+agg1 region
    int* ints       = (int*)(us + (size_t)n * 192);
    int* row_ptr    = ints;                    // n+1
    int* hist       = ints + (n + 1);          // n
    int* rank       = ints + (n + 1) + n;      // E
    int* sorted_src = rank + nE;               // E
    int* bsum       = sorted_src + nE;         // <=64
    int* boffs      = bsum + 64;               // <=64

    const int EB = (nE + 255) / 256;
    const int NB = (n + 255) / 256;
    const int CB = (n + 127) / 128;
    const int SB = (n + SCAN_CHUNK - 1) / SCAN_CHUNK;

    // --- CSR build ---
    hipMemsetAsync(hist, 0, (size_t)n * sizeof(int), stream);
    k_hist<<<EB, 256, 0, stream>>>(dst, hist, rank, nE);
    k_scan_part<<<SB, 256, 0, stream>>>(hist, bsum, n);
    k_scan_mid<<<1, 64, 0, stream>>>(bsum, boffs, row_ptr, SB, n);
    k_scan_apply<<<SB, 256, 0, stream>>>(hist, boffs, row_ptr, n);
    k_scatteridx<<<EB, 256, 0, stream>>>(src, dst, row_ptr, rank, sorted_src, nE);

    // --- forward ---
    k_pre<<<NB, 256, 0, stream>>>(x, shape_emb, color_emb, W_pre, b_pre, h1B, n);
    k_agg<32, 4><<<((size_t)n * 4 + 255) / 256, 256, 0, stream>>>(row_ptr, sorted_src, h1B, agg1B, n);
    k_conv_mfma<32><<<CB, 256, 0, stream>>>(agg1B, h1B, W_rel1, b_rel1, W_root1, h2B, n);
    k_agg<64, 8><<<((size_t)n * 8 + 255) / 256, 256, 0, stream>>>(row_ptr, sorted_src, h2B, agg2B, n);
    k_conv_mfma<64><<<CB, 256, 0, stream>>>(agg2B, h2B, W_rel2, b_rel2, W_root2, h3B, n);
    k_pool_cls<<<G, 256, 0, stream>>>(h3B, batch, W_cls, b_cls, (float*)d_out, n);
}